// Round 1
// baseline (437.445 us; speedup 1.0000x reference)
//
#include <hip/hip_runtime.h>

// GCN: h1 = relu(Agg(x@W1)+b1); h2 = relu(Agg(h1@W2)+b2); out = mean(h2)@Wc+bc
// Agg uses norm(r,c)=dinv[r]*dinv[c] which factors: prescale rows by dinv in
// GEMM epilogue, pull-accumulate via CSR (built per call), postscale+bias+relu.

constexpr int N = 50000;
constexpr int E = 800000;
constexpr int D = 128;
constexpr int DOUT = 40;
constexpr int NB_SCAN = (N + 1023) / 1024;   // 49

// ---------------- CSR build ----------------
__global__ void k_count(const int* __restrict__ col, int* __restrict__ cnt) {
    int e = blockIdx.x * 256 + threadIdx.x;
    if (e < E) atomicAdd(&cnt[col[e]], 1);
}

__global__ void k_scan1(const int* __restrict__ cnt, int* __restrict__ ofs,
                        int* __restrict__ bsum) {
    __shared__ int buf[1024];
    int t = threadIdx.x;
    int i = blockIdx.x * 1024 + t;
    int v = (i < N) ? cnt[i] : 0;
    buf[t] = v;
    __syncthreads();
    for (int d = 1; d < 1024; d <<= 1) {
        int add = (t >= d) ? buf[t - d] : 0;
        __syncthreads();
        buf[t] += add;
        __syncthreads();
    }
    if (i < N) ofs[i] = buf[t] - v;            // block-local exclusive
    if (t == 1023) bsum[blockIdx.x] = buf[1023];
}

__global__ void k_scan2(int* __restrict__ bsum) {   // 1 block, 64 threads
    __shared__ int buf[64];
    int t = threadIdx.x;
    int v = (t < NB_SCAN) ? bsum[t] : 0;
    buf[t] = v;
    __syncthreads();
    for (int d = 1; d < 64; d <<= 1) {
        int add = (t >= d) ? buf[t - d] : 0;
        __syncthreads();
        buf[t] += add;
        __syncthreads();
    }
    if (t < NB_SCAN) bsum[t] = buf[t] - v;     // exclusive over block sums
}

__global__ void k_scan3(int* __restrict__ ofs, int* __restrict__ cursor,
                        const int* __restrict__ bsum, const int* __restrict__ cnt,
                        float* __restrict__ dinv) {
    int i = blockIdx.x * 1024 + threadIdx.x;
    if (i < N) {
        int o = ofs[i] + bsum[blockIdx.x];
        ofs[i] = o;
        cursor[i] = o;
        dinv[i] = rsqrtf((float)(cnt[i] + 1));   // +1 self loop; always > 0
    }
    if (i == 0) ofs[N] = E;
}

__global__ void k_bucket(const int* __restrict__ ei, int* __restrict__ cursor,
                         int* __restrict__ csr) {
    int e = blockIdx.x * 256 + threadIdx.x;
    if (e < E) {
        int r = ei[e];         // source
        int c = ei[E + e];     // destination
        int p = atomicAdd(&cursor[c], 1);
        csr[p] = r;
    }
}

// ---------------- GEMM: out[r] = dinv[r] * (A[r] @ W), A: [M x 128], W: [128 x 128]
__global__ __launch_bounds__(256) void k_gemm(const float* __restrict__ A,
                                              const float* __restrict__ W,
                                              const float* __restrict__ dinv,
                                              float* __restrict__ out, int M) {
    __shared__ float As[32][128];   // [k][row]
    __shared__ float Bs[32][128];   // [k][col]
    int tid = threadIdx.x;
    int tx = tid & 15, ty = tid >> 4;
    int row0 = blockIdx.x * 128;
    float acc[8][8] = {};

    for (int kt = 0; kt < 128; kt += 32) {
        // A tile: 128 rows x 32 k, transposed into As[k][row]
        {
            int r = tid >> 1;
            int kk = (tid & 1) * 16;
            int grow = row0 + r;
#pragma unroll
            for (int q = 0; q < 4; ++q) {
                float4 v = make_float4(0.f, 0.f, 0.f, 0.f);
                if (grow < M) v = *(const float4*)&A[(size_t)grow * D + kt + kk + q * 4];
                As[kk + q * 4 + 0][r] = v.x;
                As[kk + q * 4 + 1][r] = v.y;
                As[kk + q * 4 + 2][r] = v.z;
                As[kk + q * 4 + 3][r] = v.w;
            }
        }
        // B tile: 32 k x 128 cols
        {
            int kb = tid >> 3;
            int cb = (tid & 7) * 16;
#pragma unroll
            for (int q = 0; q < 4; ++q) {
                *(float4*)&Bs[kb][cb + q * 4] =
                    *(const float4*)&W[(size_t)(kt + kb) * D + cb + q * 4];
            }
        }
        __syncthreads();
#pragma unroll
        for (int k = 0; k < 32; ++k) {
            float a[8], b[8];
            *(float4*)&a[0] = *(const float4*)&As[k][ty * 8];
            *(float4*)&a[4] = *(const float4*)&As[k][ty * 8 + 4];
            *(float4*)&b[0] = *(const float4*)&Bs[k][tx * 8];
            *(float4*)&b[4] = *(const float4*)&Bs[k][tx * 8 + 4];
#pragma unroll
            for (int i = 0; i < 8; ++i)
#pragma unroll
                for (int j = 0; j < 8; ++j)
                    acc[i][j] = fmaf(a[i], b[j], acc[i][j]);
        }
        __syncthreads();
    }

#pragma unroll
    for (int i = 0; i < 8; ++i) {
        int r = row0 + ty * 8 + i;
        if (r < M) {
            float s = dinv[r];
#pragma unroll
            for (int j = 0; j < 8; j += 4) {
                float4 v;
                v.x = acc[i][j + 0] * s;
                v.y = acc[i][j + 1] * s;
                v.z = acc[i][j + 2] * s;
                v.w = acc[i][j + 3] * s;
                *(float4*)&out[(size_t)r * D + tx * 8 + j] = v;
            }
        }
    }
}

// ---------------- Aggregation (pull, 1 wave per node) ----------------
// out[c] = relu(dinv[c] * (hs[c] + sum_{r in in(c)} hs[r]) + bias)
__global__ __launch_bounds__(256) void k_agg(const float* __restrict__ hs,
                                             const int* __restrict__ ofs,
                                             const int* __restrict__ csr,
                                             const float* __restrict__ dinv,
                                             const float* __restrict__ bias,
                                             float* __restrict__ out) {
    int wave = threadIdx.x >> 6;
    int lane = threadIdx.x & 63;
    int c = blockIdx.x * 4 + wave;
    if (c >= N) return;
    int e0 = ofs[c], e1 = ofs[c + 1];
    float2 s = *(const float2*)&hs[(size_t)c * D + lane * 2];   // self loop
    for (int j = e0; j < e1; ++j) {
        int r = csr[j];
        float2 v = *(const float2*)&hs[(size_t)r * D + lane * 2];
        s.x += v.x;
        s.y += v.y;
    }
    float dc = dinv[c];
    float2 b = *(const float2*)&bias[lane * 2];
    float2 o;
    o.x = fmaxf(fmaf(dc, s.x, b.x), 0.f);
    o.y = fmaxf(fmaf(dc, s.y, b.y), 0.f);
    *(float2*)&out[(size_t)c * D + lane * 2] = o;
}

// ---------------- Mean pool (stage 1): gpart[b][d] = sum over block's rows
__global__ __launch_bounds__(256) void k_pool(const float* __restrict__ h,
                                              float* __restrict__ gpart) {
    int d = threadIdx.x & 127;
    int half = threadIdx.x >> 7;
    int b = blockIdx.x;                 // 256 blocks
    int per = (N + 255) / 256;          // 196
    int r0 = b * per;
    int r1 = r0 + per;
    if (r1 > N) r1 = N;
    float acc = 0.f;
    for (int r = r0 + half; r < r1; r += 2)
        acc += h[(size_t)r * D + d];
    __shared__ float red[256];
    red[threadIdx.x] = acc;
    __syncthreads();
    if (half == 0) gpart[(size_t)b * D + d] = red[d] + red[128 + d];
}

// ---------------- Final: g = sum(gpart)/N; out = g@Wc + bc
__global__ void k_final(const float* __restrict__ gpart, const float* __restrict__ Wc,
                        const float* __restrict__ bc, float* __restrict__ out) {
    __shared__ float g[D];
    int t = threadIdx.x;   // 128 threads
    float s = 0.f;
    for (int w = 0; w < 256; ++w) s += gpart[(size_t)w * D + t];
    g[t] = s * (1.0f / (float)N);
    __syncthreads();
    if (t < DOUT) {
        float acc = bc[t];
        for (int d = 0; d < D; ++d) acc = fmaf(g[d], Wc[d * DOUT + t], acc);
        out[t] = acc;
    }
}

extern "C" void kernel_launch(void* const* d_in, const int* in_sizes, int n_in,
                              void* d_out, int out_size, void* d_ws, size_t ws_size,
                              hipStream_t stream) {
    const float* x  = (const float*)d_in[0];
    const int*   ei = (const int*)d_in[1];
    const float* W1 = (const float*)d_in[2];
    const float* b1 = (const float*)d_in[3];
    const float* W2 = (const float*)d_in[4];
    const float* b2 = (const float*)d_in[5];
    const float* Wc = (const float*)d_in[6];
    const float* bc = (const float*)d_in[7];
    float* out = (float*)d_out;

    char* ws = (char*)d_ws;
    size_t off = 0;
    auto alloc = [&](size_t bytes) {
        void* p = ws + off;
        off += (bytes + 511) & ~(size_t)511;
        return p;
    };
    int*   cnt    = (int*)  alloc((size_t)N * 4);
    int*   ofs    = (int*)  alloc((size_t)(N + 1) * 4);
    int*   cursor = (int*)  alloc((size_t)N * 4);
    float* dinv   = (float*)alloc((size_t)N * 4);
    int*   bsum   = (int*)  alloc(64 * 4);
    int*   csr    = (int*)  alloc((size_t)E * 4);
    float* hsA    = (float*)alloc((size_t)N * D * 4);
    float* hactB  = (float*)alloc((size_t)N * D * 4);
    float* gpart  = (float*)alloc((size_t)256 * D * 4);
    (void)ws_size; (void)in_sizes; (void)n_in; (void)out_size;

    const int* col = ei + E;

    hipMemsetAsync(cnt, 0, (size_t)N * 4, stream);

    int gE = (E + 255) / 256;
    k_count<<<gE, 256, 0, stream>>>(col, cnt);
    k_scan1<<<NB_SCAN, 1024, 0, stream>>>(cnt, ofs, bsum);
    k_scan2<<<1, 64, 0, stream>>>(bsum);
    k_scan3<<<NB_SCAN, 1024, 0, stream>>>(ofs, cursor, bsum, cnt, dinv);
    k_bucket<<<gE, 256, 0, stream>>>(ei, cursor, csr);

    int gM = (N + 127) / 128;   // 391
    int gA = (N + 3) / 4;       // 12500

    // layer 1
    k_gemm<<<gM, 256, 0, stream>>>(x, W1, dinv, hsA, N);
    k_agg<<<gA, 256, 0, stream>>>(hsA, ofs, csr, dinv, b1, hactB);
    // layer 2
    k_gemm<<<gM, 256, 0, stream>>>(hactB, W2, dinv, hsA, N);
    k_agg<<<gA, 256, 0, stream>>>(hsA, ofs, csr, dinv, b2, hactB);
    // pool + classify
    k_pool<<<256, 256, 0, stream>>>(hactB, gpart);
    k_final<<<1, 128, 0, stream>>>(gpart, Wc, bc, out);
}

// Round 2
// 379.083 us; speedup vs baseline: 1.1540x; 1.1540x over previous
//
#include <hip/hip_runtime.h>

// GCN: h1 = relu(Agg(x@W1)+b1); h2 = relu(Agg(h1@W2)+b2); out = mean(h2)@Wc+bc
// Agg uses norm(r,c)=dinv[r]*dinv[c] which factors: prescale rows by dinv in
// GEMM epilogue, pull-accumulate via CSR (built per call), postscale+bias+relu.
// R1: k_agg rewritten for MLP — float4 lanes, half-wave per edge, 4-deep
// unroll => 8 edge-row loads in flight per wave (was ~1, latency-bound).

constexpr int N = 50000;
constexpr int E = 800000;
constexpr int D = 128;
constexpr int DOUT = 40;
constexpr int NB_SCAN = (N + 1023) / 1024;   // 49

// ---------------- CSR build ----------------
__global__ void k_count(const int* __restrict__ col, int* __restrict__ cnt) {
    int e = blockIdx.x * 256 + threadIdx.x;
    if (e < E) atomicAdd(&cnt[col[e]], 1);
}

__global__ void k_scan1(const int* __restrict__ cnt, int* __restrict__ ofs,
                        int* __restrict__ bsum) {
    __shared__ int buf[1024];
    int t = threadIdx.x;
    int i = blockIdx.x * 1024 + t;
    int v = (i < N) ? cnt[i] : 0;
    buf[t] = v;
    __syncthreads();
    for (int d = 1; d < 1024; d <<= 1) {
        int add = (t >= d) ? buf[t - d] : 0;
        __syncthreads();
        buf[t] += add;
        __syncthreads();
    }
    if (i < N) ofs[i] = buf[t] - v;            // block-local exclusive
    if (t == 1023) bsum[blockIdx.x] = buf[1023];
}

__global__ void k_scan2(int* __restrict__ bsum) {   // 1 block, 64 threads
    __shared__ int buf[64];
    int t = threadIdx.x;
    int v = (t < NB_SCAN) ? bsum[t] : 0;
    buf[t] = v;
    __syncthreads();
    for (int d = 1; d < 64; d <<= 1) {
        int add = (t >= d) ? buf[t - d] : 0;
        __syncthreads();
        buf[t] += add;
        __syncthreads();
    }
    if (t < NB_SCAN) bsum[t] = buf[t] - v;     // exclusive over block sums
}

__global__ void k_scan3(int* __restrict__ ofs, int* __restrict__ cursor,
                        const int* __restrict__ bsum, const int* __restrict__ cnt,
                        float* __restrict__ dinv) {
    int i = blockIdx.x * 1024 + threadIdx.x;
    if (i < N) {
        int o = ofs[i] + bsum[blockIdx.x];
        ofs[i] = o;
        cursor[i] = o;
        dinv[i] = rsqrtf((float)(cnt[i] + 1));   // +1 self loop; always > 0
    }
    if (i == 0) ofs[N] = E;
}

__global__ void k_bucket(const int* __restrict__ ei, int* __restrict__ cursor,
                         int* __restrict__ csr) {
    int e = blockIdx.x * 256 + threadIdx.x;
    if (e < E) {
        int r = ei[e];         // source
        int c = ei[E + e];     // destination
        int p = atomicAdd(&cursor[c], 1);
        csr[p] = r;
    }
}

// ---------------- GEMM: out[r] = dinv[r] * (A[r] @ W), A: [M x 128], W: [128 x 128]
__global__ __launch_bounds__(256) void k_gemm(const float* __restrict__ A,
                                              const float* __restrict__ W,
                                              const float* __restrict__ dinv,
                                              float* __restrict__ out, int M) {
    __shared__ float As[32][128];   // [k][row]
    __shared__ float Bs[32][128];   // [k][col]
    int tid = threadIdx.x;
    int tx = tid & 15, ty = tid >> 4;
    int row0 = blockIdx.x * 128;
    float acc[8][8] = {};

    for (int kt = 0; kt < 128; kt += 32) {
        // A tile: 128 rows x 32 k, transposed into As[k][row]
        {
            int r = tid >> 1;
            int kk = (tid & 1) * 16;
            int grow = row0 + r;
#pragma unroll
            for (int q = 0; q < 4; ++q) {
                float4 v = make_float4(0.f, 0.f, 0.f, 0.f);
                if (grow < M) v = *(const float4*)&A[(size_t)grow * D + kt + kk + q * 4];
                As[kk + q * 4 + 0][r] = v.x;
                As[kk + q * 4 + 1][r] = v.y;
                As[kk + q * 4 + 2][r] = v.z;
                As[kk + q * 4 + 3][r] = v.w;
            }
        }
        // B tile: 32 k x 128 cols
        {
            int kb = tid >> 3;
            int cb = (tid & 7) * 16;
#pragma unroll
            for (int q = 0; q < 4; ++q) {
                *(float4*)&Bs[kb][cb + q * 4] =
                    *(const float4*)&W[(size_t)(kt + kb) * D + cb + q * 4];
            }
        }
        __syncthreads();
#pragma unroll
        for (int k = 0; k < 32; ++k) {
            float a[8], b[8];
            *(float4*)&a[0] = *(const float4*)&As[k][ty * 8];
            *(float4*)&a[4] = *(const float4*)&As[k][ty * 8 + 4];
            *(float4*)&b[0] = *(const float4*)&Bs[k][tx * 8];
            *(float4*)&b[4] = *(const float4*)&Bs[k][tx * 8 + 4];
#pragma unroll
            for (int i = 0; i < 8; ++i)
#pragma unroll
                for (int j = 0; j < 8; ++j)
                    acc[i][j] = fmaf(a[i], b[j], acc[i][j]);
        }
        __syncthreads();
    }

#pragma unroll
    for (int i = 0; i < 8; ++i) {
        int r = row0 + ty * 8 + i;
        if (r < M) {
            float s = dinv[r];
#pragma unroll
            for (int j = 0; j < 8; j += 4) {
                float4 v;
                v.x = acc[i][j + 0] * s;
                v.y = acc[i][j + 1] * s;
                v.z = acc[i][j + 2] * s;
                v.w = acc[i][j + 3] * s;
                *(float4*)&out[(size_t)r * D + tx * 8 + j] = v;
            }
        }
    }
}

// ---------------- Aggregation (pull, 1 wave per node, MLP-optimized) ------
// out[c] = relu(dinv[c] * (hs[c] + sum_{r in in(c)} hs[r]) + bias)
// lane = h*32+q: half-wave h handles alternating edges, q indexes float4 col.
// 4-deep unroll with 4 accumulators => up to 8 edge-rows in flight per wave.
__device__ __forceinline__ void f4add(float4& a, const float4& v) {
    a.x += v.x; a.y += v.y; a.z += v.z; a.w += v.w;
}

__global__ __launch_bounds__(256) void k_agg(const float4* __restrict__ hs4,
                                             const int* __restrict__ ofs,
                                             const int* __restrict__ csr,
                                             const float* __restrict__ dinv,
                                             const float4* __restrict__ bias4,
                                             float4* __restrict__ out4) {
    int wave = threadIdx.x >> 6;
    int lane = threadIdx.x & 63;
    int h = lane >> 5;          // half-wave id 0/1
    int q = lane & 31;          // float4 column
    int c = blockIdx.x * 4 + wave;
    if (c >= N) return;
    int e0 = ofs[c], e1 = ofs[c + 1];

    float4 z = make_float4(0.f, 0.f, 0.f, 0.f);
    float4 a0 = z, a1 = z, a2 = z, a3 = z;
    if (h == 0) a0 = hs4[(size_t)c * 32 + q];        // self loop on half 0

    int j = e0;
    // main: 8 edges per iteration (4 per half-wave), 4 independent loads/lane
    for (; j + 8 <= e1; j += 8) {
        int r0 = csr[j + 0 + h];
        int r1 = csr[j + 2 + h];
        int r2 = csr[j + 4 + h];
        int r3 = csr[j + 6 + h];
        float4 v0 = hs4[(size_t)r0 * 32 + q];
        float4 v1 = hs4[(size_t)r1 * 32 + q];
        float4 v2 = hs4[(size_t)r2 * 32 + q];
        float4 v3 = hs4[(size_t)r3 * 32 + q];
        f4add(a0, v0); f4add(a1, v1); f4add(a2, v2); f4add(a3, v3);
    }
    // tail: 2 edges per iteration
    for (; j + 2 <= e1; j += 2) {
        int r0 = csr[j + h];
        float4 v0 = hs4[(size_t)r0 * 32 + q];
        f4add(a0, v0);
    }
    // last odd edge: half 0 only
    if (j < e1 && h == 0) {
        int r0 = csr[j];
        float4 v0 = hs4[(size_t)r0 * 32 + q];
        f4add(a0, v0);
    }

    f4add(a0, a1); f4add(a2, a3); f4add(a0, a2);
    // combine the two half-waves (lane ^ 32)
    a0.x += __shfl_xor(a0.x, 32, 64);
    a0.y += __shfl_xor(a0.y, 32, 64);
    a0.z += __shfl_xor(a0.z, 32, 64);
    a0.w += __shfl_xor(a0.w, 32, 64);

    if (h == 0) {
        float dc = dinv[c];
        float4 b = bias4[q];
        float4 o;
        o.x = fmaxf(fmaf(dc, a0.x, b.x), 0.f);
        o.y = fmaxf(fmaf(dc, a0.y, b.y), 0.f);
        o.z = fmaxf(fmaf(dc, a0.z, b.z), 0.f);
        o.w = fmaxf(fmaf(dc, a0.w, b.w), 0.f);
        out4[(size_t)c * 32 + q] = o;
    }
}

// ---------------- Mean pool (stage 1): gpart[b][d] = sum over block's rows
__global__ __launch_bounds__(256) void k_pool(const float* __restrict__ h,
                                              float* __restrict__ gpart) {
    int d = threadIdx.x & 127;
    int half = threadIdx.x >> 7;
    int b = blockIdx.x;                 // 256 blocks
    int per = (N + 255) / 256;          // 196
    int r0 = b * per;
    int r1 = r0 + per;
    if (r1 > N) r1 = N;
    float acc = 0.f;
    for (int r = r0 + half; r < r1; r += 2)
        acc += h[(size_t)r * D + d];
    __shared__ float red[256];
    red[threadIdx.x] = acc;
    __syncthreads();
    if (half == 0) gpart[(size_t)b * D + d] = red[d] + red[128 + d];
}

// ---------------- Final: g = sum(gpart)/N; out = g@Wc + bc  (512 threads)
__global__ __launch_bounds__(512) void k_final(const float* __restrict__ gpart,
                                               const float* __restrict__ Wc,
                                               const float* __restrict__ bc,
                                               float* __restrict__ out) {
    __shared__ float g[D];
    __shared__ float red[512];
    int t = threadIdx.x;
    int d = t & 127, grp = t >> 7;      // 4 groups, 64 partials each
    float s = 0.f;
#pragma unroll 4
    for (int w = grp * 64; w < grp * 64 + 64; ++w)
        s += gpart[(size_t)w * D + d];
    red[t] = s;
    __syncthreads();
    if (grp == 0)
        g[d] = (red[d] + red[128 + d] + red[256 + d] + red[384 + d]) * (1.0f / (float)N);
    __syncthreads();
    if (t < DOUT) {
        float acc = bc[t];
        for (int dd = 0; dd < D; ++dd) acc = fmaf(g[dd], Wc[dd * DOUT + t], acc);
        out[t] = acc;
    }
}

extern "C" void kernel_launch(void* const* d_in, const int* in_sizes, int n_in,
                              void* d_out, int out_size, void* d_ws, size_t ws_size,
                              hipStream_t stream) {
    const float* x  = (const float*)d_in[0];
    const int*   ei = (const int*)d_in[1];
    const float* W1 = (const float*)d_in[2];
    const float* b1 = (const float*)d_in[3];
    const float* W2 = (const float*)d_in[4];
    const float* b2 = (const float*)d_in[5];
    const float* Wc = (const float*)d_in[6];
    const float* bc = (const float*)d_in[7];
    float* out = (float*)d_out;

    char* ws = (char*)d_ws;
    size_t off = 0;
    auto alloc = [&](size_t bytes) {
        void* p = ws + off;
        off += (bytes + 511) & ~(size_t)511;
        return p;
    };
    int*   cnt    = (int*)  alloc((size_t)N * 4);
    int*   ofs    = (int*)  alloc((size_t)(N + 1) * 4);
    int*   cursor = (int*)  alloc((size_t)N * 4);
    float* dinv   = (float*)alloc((size_t)N * 4);
    int*   bsum   = (int*)  alloc(64 * 4);
    int*   csr    = (int*)  alloc((size_t)E * 4);
    float* hsA    = (float*)alloc((size_t)N * D * 4);
    float* hactB  = (float*)alloc((size_t)N * D * 4);
    float* gpart  = (float*)alloc((size_t)256 * D * 4);
    (void)ws_size; (void)in_sizes; (void)n_in; (void)out_size;

    const int* col = ei + E;

    hipMemsetAsync(cnt, 0, (size_t)N * 4, stream);

    int gE = (E + 255) / 256;
    k_count<<<gE, 256, 0, stream>>>(col, cnt);
    k_scan1<<<NB_SCAN, 1024, 0, stream>>>(cnt, ofs, bsum);
    k_scan2<<<1, 64, 0, stream>>>(bsum);
    k_scan3<<<NB_SCAN, 1024, 0, stream>>>(ofs, cursor, bsum, cnt, dinv);
    k_bucket<<<gE, 256, 0, stream>>>(ei, cursor, csr);

    int gM = (N + 127) / 128;   // 391
    int gA = (N + 3) / 4;       // 12500

    // layer 1
    k_gemm<<<gM, 256, 0, stream>>>(x, W1, dinv, hsA, N);
    k_agg<<<gA, 256, 0, stream>>>((const float4*)hsA, ofs, csr, dinv,
                                  (const float4*)b1, (float4*)hactB);
    // layer 2
    k_gemm<<<gM, 256, 0, stream>>>(hactB, W2, dinv, hsA, N);
    k_agg<<<gA, 256, 0, stream>>>((const float4*)hsA, ofs, csr, dinv,
                                  (const float4*)b2, (float4*)hactB);
    // pool + classify
    k_pool<<<256, 256, 0, stream>>>(hactB, gpart);
    k_final<<<1, 512, 0, stream>>>(gpart, Wc, bc, out);
}

// Round 3
// 378.993 us; speedup vs baseline: 1.1542x; 1.0002x over previous
//
#include <hip/hip_runtime.h>

// GCN: h1 = relu(Agg(x@W1)+b1); h2 = relu(Agg(h1@W2)+b2); out = mean(h2)@Wc+bc
// Agg uses norm(r,c)=dinv[r]*dinv[c] which factors: prescale rows by dinv in
// GEMM epilogue, pull-accumulate via CSR (built per call), postscale+bias+relu.
// R1: k_agg MLP — float4 lanes, half-wave/edge, 4-deep unroll.
// R2: k_count/k_bucket ×4 edge ILP (4 independent atomics in flight per
//     thread; was 1 → 58µs latency-bound at VALUBusy 0.3%). k_agg 4-edge tail.

constexpr int N = 50000;
constexpr int E = 800000;
constexpr int D = 128;
constexpr int DOUT = 40;
constexpr int NB_SCAN = (N + 1023) / 1024;   // 49
constexpr int T4 = E / 4;                    // 200000 threads for edge kernels

// ---------------- CSR build ----------------
__global__ void k_count(const int* __restrict__ col, int* __restrict__ cnt) {
    int t = blockIdx.x * 256 + threadIdx.x;
    if (t >= T4) return;
    int c0 = col[t];
    int c1 = col[t + T4];
    int c2 = col[t + 2 * T4];
    int c3 = col[t + 3 * T4];
    atomicAdd(&cnt[c0], 1);
    atomicAdd(&cnt[c1], 1);
    atomicAdd(&cnt[c2], 1);
    atomicAdd(&cnt[c3], 1);
}

__global__ void k_scan1(const int* __restrict__ cnt, int* __restrict__ ofs,
                        int* __restrict__ bsum) {
    __shared__ int buf[1024];
    int t = threadIdx.x;
    int i = blockIdx.x * 1024 + t;
    int v = (i < N) ? cnt[i] : 0;
    buf[t] = v;
    __syncthreads();
    for (int d = 1; d < 1024; d <<= 1) {
        int add = (t >= d) ? buf[t - d] : 0;
        __syncthreads();
        buf[t] += add;
        __syncthreads();
    }
    if (i < N) ofs[i] = buf[t] - v;            // block-local exclusive
    if (t == 1023) bsum[blockIdx.x] = buf[1023];
}

__global__ void k_scan2(int* __restrict__ bsum) {   // 1 block, 64 threads
    __shared__ int buf[64];
    int t = threadIdx.x;
    int v = (t < NB_SCAN) ? bsum[t] : 0;
    buf[t] = v;
    __syncthreads();
    for (int d = 1; d < 64; d <<= 1) {
        int add = (t >= d) ? buf[t - d] : 0;
        __syncthreads();
        buf[t] += add;
        __syncthreads();
    }
    if (t < NB_SCAN) bsum[t] = buf[t] - v;     // exclusive over block sums
}

__global__ void k_scan3(int* __restrict__ ofs, int* __restrict__ cursor,
                        const int* __restrict__ bsum, const int* __restrict__ cnt,
                        float* __restrict__ dinv) {
    int i = blockIdx.x * 1024 + threadIdx.x;
    if (i < N) {
        int o = ofs[i] + bsum[blockIdx.x];
        ofs[i] = o;
        cursor[i] = o;
        dinv[i] = rsqrtf((float)(cnt[i] + 1));   // +1 self loop; always > 0
    }
    if (i == 0) ofs[N] = E;
}

__global__ void k_bucket(const int* __restrict__ ei, int* __restrict__ cursor,
                         int* __restrict__ csr) {
    int t = blockIdx.x * 256 + threadIdx.x;
    if (t >= T4) return;
    int e0 = t, e1 = t + T4, e2 = t + 2 * T4, e3 = t + 3 * T4;
    int c0 = ei[E + e0], c1 = ei[E + e1], c2 = ei[E + e2], c3 = ei[E + e3];
    int r0 = ei[e0], r1 = ei[e1], r2 = ei[e2], r3 = ei[e3];
    int p0 = atomicAdd(&cursor[c0], 1);
    int p1 = atomicAdd(&cursor[c1], 1);
    int p2 = atomicAdd(&cursor[c2], 1);
    int p3 = atomicAdd(&cursor[c3], 1);
    csr[p0] = r0;
    csr[p1] = r1;
    csr[p2] = r2;
    csr[p3] = r3;
}

// ---------------- GEMM: out[r] = dinv[r] * (A[r] @ W), A: [M x 128], W: [128 x 128]
__global__ __launch_bounds__(256) void k_gemm(const float* __restrict__ A,
                                              const float* __restrict__ W,
                                              const float* __restrict__ dinv,
                                              float* __restrict__ out, int M) {
    __shared__ float As[32][128];   // [k][row]
    __shared__ float Bs[32][128];   // [k][col]
    int tid = threadIdx.x;
    int tx = tid & 15, ty = tid >> 4;
    int row0 = blockIdx.x * 128;
    float acc[8][8] = {};

    for (int kt = 0; kt < 128; kt += 32) {
        // A tile: 128 rows x 32 k, transposed into As[k][row]
        {
            int r = tid >> 1;
            int kk = (tid & 1) * 16;
            int grow = row0 + r;
#pragma unroll
            for (int q = 0; q < 4; ++q) {
                float4 v = make_float4(0.f, 0.f, 0.f, 0.f);
                if (grow < M) v = *(const float4*)&A[(size_t)grow * D + kt + kk + q * 4];
                As[kk + q * 4 + 0][r] = v.x;
                As[kk + q * 4 + 1][r] = v.y;
                As[kk + q * 4 + 2][r] = v.z;
                As[kk + q * 4 + 3][r] = v.w;
            }
        }
        // B tile: 32 k x 128 cols
        {
            int kb = tid >> 3;
            int cb = (tid & 7) * 16;
#pragma unroll
            for (int q = 0; q < 4; ++q) {
                *(float4*)&Bs[kb][cb + q * 4] =
                    *(const float4*)&W[(size_t)(kt + kb) * D + cb + q * 4];
            }
        }
        __syncthreads();
#pragma unroll
        for (int k = 0; k < 32; ++k) {
            float a[8], b[8];
            *(float4*)&a[0] = *(const float4*)&As[k][ty * 8];
            *(float4*)&a[4] = *(const float4*)&As[k][ty * 8 + 4];
            *(float4*)&b[0] = *(const float4*)&Bs[k][tx * 8];
            *(float4*)&b[4] = *(const float4*)&Bs[k][tx * 8 + 4];
#pragma unroll
            for (int i = 0; i < 8; ++i)
#pragma unroll
                for (int j = 0; j < 8; ++j)
                    acc[i][j] = fmaf(a[i], b[j], acc[i][j]);
        }
        __syncthreads();
    }

#pragma unroll
    for (int i = 0; i < 8; ++i) {
        int r = row0 + ty * 8 + i;
        if (r < M) {
            float s = dinv[r];
#pragma unroll
            for (int j = 0; j < 8; j += 4) {
                float4 v;
                v.x = acc[i][j + 0] * s;
                v.y = acc[i][j + 1] * s;
                v.z = acc[i][j + 2] * s;
                v.w = acc[i][j + 3] * s;
                *(float4*)&out[(size_t)r * D + tx * 8 + j] = v;
            }
        }
    }
}

// ---------------- Aggregation (pull, 1 wave per node, MLP-optimized) ------
// out[c] = relu(dinv[c] * (hs[c] + sum_{r in in(c)} hs[r]) + bias)
__device__ __forceinline__ void f4add(float4& a, const float4& v) {
    a.x += v.x; a.y += v.y; a.z += v.z; a.w += v.w;
}

__global__ __launch_bounds__(256) void k_agg(const float4* __restrict__ hs4,
                                             const int* __restrict__ ofs,
                                             const int* __restrict__ csr,
                                             const float* __restrict__ dinv,
                                             const float4* __restrict__ bias4,
                                             float4* __restrict__ out4) {
    int wave = threadIdx.x >> 6;
    int lane = threadIdx.x & 63;
    int h = lane >> 5;          // half-wave id 0/1
    int q = lane & 31;          // float4 column
    int c = blockIdx.x * 4 + wave;
    if (c >= N) return;
    int e0 = ofs[c], e1 = ofs[c + 1];

    float4 z = make_float4(0.f, 0.f, 0.f, 0.f);
    float4 a0 = z, a1 = z, a2 = z, a3 = z;
    if (h == 0) a0 = hs4[(size_t)c * 32 + q];        // self loop on half 0

    int j = e0;
    // main: 8 edges per iteration (4 per half-wave), 4 independent loads/lane
    for (; j + 8 <= e1; j += 8) {
        int r0 = csr[j + 0 + h];
        int r1 = csr[j + 2 + h];
        int r2 = csr[j + 4 + h];
        int r3 = csr[j + 6 + h];
        float4 v0 = hs4[(size_t)r0 * 32 + q];
        float4 v1 = hs4[(size_t)r1 * 32 + q];
        float4 v2 = hs4[(size_t)r2 * 32 + q];
        float4 v3 = hs4[(size_t)r3 * 32 + q];
        f4add(a0, v0); f4add(a1, v1); f4add(a2, v2); f4add(a3, v3);
    }
    // tail: 4 edges (2 per half-wave, 2 loads in flight)
    if (j + 4 <= e1) {
        int r0 = csr[j + 0 + h];
        int r1 = csr[j + 2 + h];
        float4 v0 = hs4[(size_t)r0 * 32 + q];
        float4 v1 = hs4[(size_t)r1 * 32 + q];
        f4add(a0, v0); f4add(a1, v1);
        j += 4;
    }
    // tail: 2 edges
    if (j + 2 <= e1) {
        int r0 = csr[j + h];
        float4 v0 = hs4[(size_t)r0 * 32 + q];
        f4add(a0, v0);
        j += 2;
    }
    // last odd edge: half 0 only
    if (j < e1 && h == 0) {
        int r0 = csr[j];
        float4 v0 = hs4[(size_t)r0 * 32 + q];
        f4add(a0, v0);
    }

    f4add(a0, a1); f4add(a2, a3); f4add(a0, a2);
    // combine the two half-waves (lane ^ 32)
    a0.x += __shfl_xor(a0.x, 32, 64);
    a0.y += __shfl_xor(a0.y, 32, 64);
    a0.z += __shfl_xor(a0.z, 32, 64);
    a0.w += __shfl_xor(a0.w, 32, 64);

    if (h == 0) {
        float dc = dinv[c];
        float4 b = bias4[q];
        float4 o;
        o.x = fmaxf(fmaf(dc, a0.x, b.x), 0.f);
        o.y = fmaxf(fmaf(dc, a0.y, b.y), 0.f);
        o.z = fmaxf(fmaf(dc, a0.z, b.z), 0.f);
        o.w = fmaxf(fmaf(dc, a0.w, b.w), 0.f);
        out4[(size_t)c * 32 + q] = o;
    }
}

// ---------------- Mean pool (stage 1): gpart[b][d] = sum over block's rows
__global__ __launch_bounds__(256) void k_pool(const float* __restrict__ h,
                                              float* __restrict__ gpart) {
    int d = threadIdx.x & 127;
    int half = threadIdx.x >> 7;
    int b = blockIdx.x;                 // 256 blocks
    int per = (N + 255) / 256;          // 196
    int r0 = b * per;
    int r1 = r0 + per;
    if (r1 > N) r1 = N;
    float acc = 0.f;
    for (int r = r0 + half; r < r1; r += 2)
        acc += h[(size_t)r * D + d];
    __shared__ float red[256];
    red[threadIdx.x] = acc;
    __syncthreads();
    if (half == 0) gpart[(size_t)b * D + d] = red[d] + red[128 + d];
}

// ---------------- Final: g = sum(gpart)/N; out = g@Wc + bc  (512 threads)
__global__ __launch_bounds__(512) void k_final(const float* __restrict__ gpart,
                                               const float* __restrict__ Wc,
                                               const float* __restrict__ bc,
                                               float* __restrict__ out) {
    __shared__ float g[D];
    __shared__ float red[512];
    int t = threadIdx.x;
    int d = t & 127, grp = t >> 7;      // 4 groups, 64 partials each
    float s = 0.f;
#pragma unroll 4
    for (int w = grp * 64; w < grp * 64 + 64; ++w)
        s += gpart[(size_t)w * D + d];
    red[t] = s;
    __syncthreads();
    if (grp == 0)
        g[d] = (red[d] + red[128 + d] + red[256 + d] + red[384 + d]) * (1.0f / (float)N);
    __syncthreads();
    if (t < DOUT) {
        float acc = bc[t];
        for (int dd = 0; dd < D; ++dd) acc = fmaf(g[dd], Wc[dd * DOUT + t], acc);
        out[t] = acc;
    }
}

extern "C" void kernel_launch(void* const* d_in, const int* in_sizes, int n_in,
                              void* d_out, int out_size, void* d_ws, size_t ws_size,
                              hipStream_t stream) {
    const float* x  = (const float*)d_in[0];
    const int*   ei = (const int*)d_in[1];
    const float* W1 = (const float*)d_in[2];
    const float* b1 = (const float*)d_in[3];
    const float* W2 = (const float*)d_in[4];
    const float* b2 = (const float*)d_in[5];
    const float* Wc = (const float*)d_in[6];
    const float* bc = (const float*)d_in[7];
    float* out = (float*)d_out;

    char* ws = (char*)d_ws;
    size_t off = 0;
    auto alloc = [&](size_t bytes) {
        void* p = ws + off;
        off += (bytes + 511) & ~(size_t)511;
        return p;
    };
    int*   cnt    = (int*)  alloc((size_t)N * 4);
    int*   ofs    = (int*)  alloc((size_t)(N + 1) * 4);
    int*   cursor = (int*)  alloc((size_t)N * 4);
    float* dinv   = (float*)alloc((size_t)N * 4);
    int*   bsum   = (int*)  alloc(64 * 4);
    int*   csr    = (int*)  alloc((size_t)E * 4);
    float* hsA    = (float*)alloc((size_t)N * D * 4);
    float* hactB  = (float*)alloc((size_t)N * D * 4);
    float* gpart  = (float*)alloc((size_t)256 * D * 4);
    (void)ws_size; (void)in_sizes; (void)n_in; (void)out_size;

    const int* col = ei + E;

    hipMemsetAsync(cnt, 0, (size_t)N * 4, stream);

    int gT = (T4 + 255) / 256;   // 782
    k_count<<<gT, 256, 0, stream>>>(col, cnt);
    k_scan1<<<NB_SCAN, 1024, 0, stream>>>(cnt, ofs, bsum);
    k_scan2<<<1, 64, 0, stream>>>(bsum);
    k_scan3<<<NB_SCAN, 1024, 0, stream>>>(ofs, cursor, bsum, cnt, dinv);
    k_bucket<<<gT, 256, 0, stream>>>(ei, cursor, csr);

    int gM = (N + 127) / 128;   // 391
    int gA = (N + 3) / 4;       // 12500

    // layer 1
    k_gemm<<<gM, 256, 0, stream>>>(x, W1, dinv, hsA, N);
    k_agg<<<gA, 256, 0, stream>>>((const float4*)hsA, ofs, csr, dinv,
                                  (const float4*)b1, (float4*)hactB);
    // layer 2
    k_gemm<<<gM, 256, 0, stream>>>(hactB, W2, dinv, hsA, N);
    k_agg<<<gA, 256, 0, stream>>>((const float4*)hsA, ofs, csr, dinv,
                                  (const float4*)b2, (float4*)hactB);
    // pool + classify
    k_pool<<<256, 256, 0, stream>>>(hactB, gpart);
    k_final<<<1, 512, 0, stream>>>(gpart, Wc, bc, out);
}